// Round 8
// baseline (174.247 us; speedup 1.0000x reference)
//
#include <hip/hip_runtime.h>
#include <hip/hip_bf16.h>

// Shapes (fixed by the problem)
#define BATCH 8
#define SEQ   2048
#define DM    768
#define DD    64   // DK == DV == 64
#define BS (BATCH * SEQ)         // 16384
#define SCALEQ 0.1803369380478f  // (1/8) * log2(e): score in log2 domain

typedef __bf16 bf16x8 __attribute__((ext_vector_type(8)));
typedef float  f32x4  __attribute__((ext_vector_type(4)));
typedef short  short8 __attribute__((ext_vector_type(8)));
typedef short  short4v __attribute__((ext_vector_type(4)));

#define MFMA16(a, b, c) __builtin_amdgcn_mfma_f32_16x16x32_bf16((a), (b), (c), 0, 0, 0)

__device__ __forceinline__ short f2bf(float x) {
    unsigned u = __builtin_bit_cast(unsigned, x);
    u = (u + 0x7fffu + ((u >> 16) & 1u)) >> 16;   // round-to-nearest-even
    return (short)u;
}
__device__ __forceinline__ float bf2f(short s) {
    unsigned u = ((unsigned)(unsigned short)s) << 16;
    return __builtin_bit_cast(float, u);
}
__device__ __forceinline__ bf16x8 cvt8(float4 a, float4 b) {
    bf16x8 r;
    r[0] = (__bf16)a.x; r[1] = (__bf16)a.y; r[2] = (__bf16)a.z; r[3] = (__bf16)a.w;
    r[4] = (__bf16)b.x; r[5] = (__bf16)b.y; r[6] = (__bf16)b.z; r[7] = (__bf16)b.w;
    return r;
}
__device__ __forceinline__ void glds16(const void* g, void* l) {
    __builtin_amdgcn_global_load_lds(
        (const __attribute__((address_space(1))) void*)g,
        (__attribute__((address_space(3))) void*)l, 16, 0, 0);
}

// ---------------------------------------------------------------------------
// Kernel 1: W [768][64] f32 -> Wt [3][64][768] bf16 (transposed, n-major).
// Wq pre-scaled by (1/8)*log2e so flash can use exp2. Zero-inits Cc.
// ---------------------------------------------------------------------------
__global__ void prep_w_kernel(const float* __restrict__ Wq, const float* __restrict__ Wk,
                              const float* __restrict__ Wv, short* __restrict__ Wt,
                              float* __restrict__ C) {
    int idx = blockIdx.x * 256 + threadIdx.x;
    if (idx < BATCH * DD) C[idx] = 0.f;
    if (idx >= 3 * DM * DD) return;
    int m = idx / (DM * DD);
    int r = (idx % (DM * DD)) / DD;
    int c = idx % DD;
    const float* W = (m == 0) ? Wq : (m == 1) ? Wk : Wv;
    float scale = (m == 0) ? SCALEQ : 1.0f;
    Wt[m * DM * DD + c * DM + r] = f2bf(W[r * DD + c] * scale);
}

// ---------------------------------------------------------------------------
// Kernel 2: projections. 32-row tiles, 128-thread (2-wave) blocks,
// 1024 blocks = 4 blocks/CU (the m97 structure ran 4/CU; 2/CU stalls on
// the per-iter barrier drain with nothing to interleave).
//  - W: double-buffered LDS via global_load_lds (lgkmcnt consumers),
//    XOR piece-swizzle -> ds_read_b128 at free 2-way aliasing.
//  - x: direct A-fragment register loads, depth-1 prefetch (vmcnt drained
//    only at the per-iter barrier).
// even blocks = Q from x1, odd = K+V from x2.
// V stored transposed [b][v][s] + fused column-sum C via f32 atomics.
// ---------------------------------------------------------------------------
__global__ __launch_bounds__(128) void proj_kernel(
        const float* __restrict__ x1, const float* __restrict__ x2,
        const short* __restrict__ Wt,
        const float* __restrict__ bq, const float* __restrict__ bk,
        const float* __restrict__ bv,
        short* __restrict__ Qs, short* __restrict__ Kb, short* __restrict__ Vtb,
        float* __restrict__ C) {
    __shared__ __align__(16) short wl[2][2][64 * 64];  // [buf][mat][n-row][64k swz]
    const int tid = threadIdx.x, wave = tid >> 6, lane = tid & 63;
    const int quad = lane >> 4, l15 = lane & 15;
    const int kv = blockIdx.x & 1;             // 0 = Q, 1 = K+V
    const int r0 = (blockIdx.x >> 1) * 32;
    const float* x = kv ? x2 : x1;
    const short* W0 = Wt + (kv ? (size_t)(DM * DD) : 0);
    const short* W1 = Wt + 2 * (size_t)(DM * DD);

    // W staging: one glds16 = 8 rows x 128B. lane -> row wrow=lane>>3,
    // slot lane&7; source piece = slot ^ (row&7) (row-base 8-aligned).
    const int wrow = lane >> 3;
    const int wpiece = ((lane & 7) ^ (lane >> 3)) * 8;

    const float* xp = x + (size_t)(r0 + wave * 16 + l15) * DM + quad * 8;

    f32x4 acc0[4] = {}, acc1[4] = {};

    // preload: W tile 0 (each wave stages 32 of the 64 n-rows) + x regs
#pragma unroll
    for (int j = 0; j < 4; j++) {
        int rbase = wave * 32 + j * 8;
        glds16(W0 + (size_t)(rbase + wrow) * DM + wpiece, &wl[0][0][rbase * 64]);
        if (kv)
            glds16(W1 + (size_t)(rbase + wrow) * DM + wpiece, &wl[0][1][rbase * 64]);
    }
    float4 c0a = *(const float4*)(xp);
    float4 c0b = *(const float4*)(xp + 4);
    float4 c1a = *(const float4*)(xp + 32);
    float4 c1b = *(const float4*)(xp + 36);
    __syncthreads();

    const int swz = l15 & 7;
#pragma unroll
    for (int it = 0; it < 12; it++) {
        const int buf = it & 1;
        float4 n0a, n0b, n1a, n1b;
        if (it < 11) {
            const int k0 = (it + 1) * 64;
#pragma unroll
            for (int j = 0; j < 4; j++) {
                int rbase = wave * 32 + j * 8;
                glds16(W0 + (size_t)(rbase + wrow) * DM + k0 + wpiece,
                       &wl[buf ^ 1][0][rbase * 64]);
                if (kv)
                    glds16(W1 + (size_t)(rbase + wrow) * DM + k0 + wpiece,
                           &wl[buf ^ 1][1][rbase * 64]);
            }
            n0a = *(const float4*)(xp + k0);
            n0b = *(const float4*)(xp + k0 + 4);
            n1a = *(const float4*)(xp + k0 + 32);
            n1b = *(const float4*)(xp + k0 + 36);
        }
#pragma unroll
        for (int kc = 0; kc < 2; kc++) {
            bf16x8 af = cvt8(kc ? c1a : c0a, kc ? c1b : c0b);
#pragma unroll
            for (int tn = 0; tn < 4; tn++) {
                const int slot = ((kc * 4 + quad) ^ swz) * 8;
                bf16x8 b0 = *(const bf16x8*)&wl[buf][0][(tn * 16 + l15) * 64 + slot];
                acc0[tn] = MFMA16(af, b0, acc0[tn]);
                if (kv) {
                    bf16x8 b1 = *(const bf16x8*)&wl[buf][1][(tn * 16 + l15) * 64 + slot];
                    acc1[tn] = MFMA16(af, b1, acc1[tn]);
                }
            }
        }
        c0a = n0a; c0b = n0b; c1a = n1a; c1b = n1b;
        __syncthreads();
    }

    if (!kv) {
#pragma unroll
        for (int tn = 0; tn < 4; tn++) {
            int v = tn * 16 + l15;
            float bb = bq[v] * SCALEQ;
#pragma unroll
            for (int r = 0; r < 4; r++)
                Qs[(size_t)(r0 + wave * 16 + quad * 4 + r) * DD + v] = f2bf(acc0[tn][r] + bb);
        }
    } else {
#pragma unroll
        for (int tn = 0; tn < 4; tn++) {
            int v = tn * 16 + l15;
            float bb = bk[v];
#pragma unroll
            for (int r = 0; r < 4; r++)
                Kb[(size_t)(r0 + wave * 16 + quad * 4 + r) * DD + v] = f2bf(acc0[tn][r] + bb);
        }
        const int b = r0 / SEQ;
        const int sbase = (r0 % SEQ) + wave * 16 + quad * 4;
#pragma unroll
        for (int tn = 0; tn < 4; tn++) {
            int v = tn * 16 + l15;
            float bb = bv[v];
            short4v pk;
            float cs = 0.f;
#pragma unroll
            for (int r = 0; r < 4; r++) {
                pk[r] = f2bf(acc1[tn][r] + bb);
                cs += bf2f(pk[r]);           // sum the rounded values (consistency)
            }
            *(short4v*)(Vtb + ((size_t)b * DD + v) * SEQ + sbase) = pk;
            cs += __shfl_xor(cs, 16);
            cs += __shfl_xor(cs, 32);
            if (quad == 0) atomicAdd(&C[b * DD + v], cs);
        }
    }
}

// ---------------------------------------------------------------------------
// Kernel 3: flash partial (round-5/7 verified structure): q-tile 64, waves
// own disjoint 256-s quarters of a 1024-s half; b = blk&7 for XCD L2
// affinity. Z^T = K.Q^T (log2 domain); per-wave LDS P^T transpose; no
// main-loop barriers. Emits 2 global halves: Yp bf16 + Dp f32.
// ---------------------------------------------------------------------------
#define PBS 72   // pbuf row stride (shorts)
__global__ __launch_bounds__(256, 2) void flash_kernel(
        const short* __restrict__ Q, const short* __restrict__ K,
        const short* __restrict__ Vt,
        short* __restrict__ Yp, float* __restrict__ Dp) {
    __shared__ __align__(16) short pbuf[4][64 * PBS];  // per-wave P^T / y-partials
    __shared__ float dl[4][64];
    const int tid  = threadIdx.x;
    const int wave = tid >> 6, lane = tid & 63, quad = lane >> 4, l15 = lane & 15;
    const int blk = blockIdx.x;
    const int b = blk & 7, qt = (blk >> 3) & 31, half = blk >> 8;
    const int q0 = qt * 64;

    bf16x8 qf[4][2];
#pragma unroll
    for (int qn = 0; qn < 4; qn++)
#pragma unroll
        for (int kc = 0; kc < 2; kc++)
            qf[qn][kc] = *(const bf16x8*)(Q + ((size_t)(b * SEQ + q0 + qn * 16 + l15)) * DD
                                          + kc * 32 + quad * 8);

    const short* Kbp = K  + (size_t)b * SEQ * DD;
    const short* Vbp = Vt + (size_t)b * DD * SEQ;
    f32x4 y[4][4] = {};          // [qn][vn]
    float den[4] = {0.f, 0.f, 0.f, 0.f};
    short* pw = &pbuf[wave][0];

    const int s_begin = half * 1024 + wave * 256;
    for (int s0 = s_begin; s0 < s_begin + 256; s0 += 64) {
        // Z^T = K.Q^T  (A = K rows s, B = Q)
#pragma unroll
        for (int tn = 0; tn < 4; tn++) {
            const short* kf = Kbp + (size_t)(s0 + tn * 16 + l15) * DD + quad * 8;
            bf16x8 ka0 = *(const bf16x8*)kf;
            bf16x8 ka1 = *(const bf16x8*)(kf + 32);
#pragma unroll
            for (int qn = 0; qn < 4; qn++) {
                f32x4 z = {0.f, 0.f, 0.f, 0.f};
                z = MFMA16(ka0, qf[qn][0], z);
                z = MFMA16(ka1, qf[qn][1], z);
                short4v pk;
#pragma unroll
                for (int r = 0; r < 4; r++) {
                    float p = __builtin_amdgcn_exp2f(z[r]);
                    den[qn] += p;
                    pk[r] = f2bf(p);
                }
                *(short4v*)&pw[(qn * 16 + l15) * PBS + tn * 16 + quad * 4] = pk;
            }
        }
        // Y^T += V^T.P^T
#pragma unroll
        for (int kc = 0; kc < 2; kc++) {
            bf16x8 pB[4];
#pragma unroll
            for (int qn = 0; qn < 4; qn++)
                pB[qn] = *(const bf16x8*)&pw[(qn * 16 + l15) * PBS + kc * 32 + quad * 8];
#pragma unroll
            for (int vn = 0; vn < 4; vn++) {
                bf16x8 va = *(const bf16x8*)(Vbp + (size_t)(vn * 16 + l15) * SEQ
                                             + s0 + kc * 32 + quad * 8);
#pragma unroll
                for (int qn = 0; qn < 4; qn++)
                    y[qn][vn] = MFMA16(va, pB[qn], y[qn][vn]);
            }
        }
    }
#pragma unroll
    for (int qn = 0; qn < 4; qn++) {
        den[qn] += __shfl_xor(den[qn], 16);
        den[qn] += __shfl_xor(den[qn], 32);
    }
#pragma unroll
    for (int qn = 0; qn < 4; qn++) {
#pragma unroll
        for (int vn = 0; vn < 4; vn++) {
            short4v pk;
#pragma unroll
            for (int r = 0; r < 4; r++) pk[r] = f2bf(y[qn][vn][r]);
            *(short4v*)&pw[(qn * 16 + l15) * PBS + vn * 16 + quad * 4] = pk;
        }
        if (quad == 0) dl[wave][qn * 16 + l15] = den[qn];
    }
    __syncthreads();
    // cross-wave reduce: wave handles q = wave*16+l15; quad covers 16 v's
    {
        const int q = wave * 16 + l15;
        float D = dl[0][q] + dl[1][q] + dl[2][q] + dl[3][q];
        float ys[16];
#pragma unroll
        for (int j = 0; j < 16; j++) ys[j] = 0.f;
#pragma unroll
        for (int u = 0; u < 4; u++) {
#pragma unroll
            for (int h = 0; h < 2; h++) {
                bf16x8 t = *(const bf16x8*)&pbuf[u][q * PBS + quad * 16 + h * 8];
#pragma unroll
                for (int j = 0; j < 8; j++) ys[h * 8 + j] += (float)t[j];
            }
        }
        const size_t row = (size_t)b * SEQ + q0 + q;
        short8 o0, o1;
#pragma unroll
        for (int j = 0; j < 8; j++) { o0[j] = f2bf(ys[j]); o1[j] = f2bf(ys[8 + j]); }
        short* yout = Yp + ((size_t)half * BS + row) * DD + quad * 16;
        *(short8*)yout = o0;
        *(short8*)(yout + 8) = o1;
        if (quad == 0) Dp[half * BS + row] = D;
    }
}

// ---------------------------------------------------------------------------
// Kernel 4: combine 2 halves + reverse transform + LayerNorm. One wave/q-row.
// ---------------------------------------------------------------------------
__global__ __launch_bounds__(256) void reduce_ln_kernel(
        const short* __restrict__ Yp, const float* __restrict__ Dp,
        const float* __restrict__ C, const float* __restrict__ gamma,
        const float* __restrict__ beta, float* __restrict__ out) {
    const int row = blockIdx.x * 4 + (threadIdx.x >> 6);
    const int v = threadIdx.x & 63;
    const int b = row >> 11;
    float Y = bf2f(Yp[(size_t)row * DD + v]) + bf2f(Yp[((size_t)BS + row) * DD + v]);
    float D = Dp[row] + Dp[BS + row];
    float attn = (C[b * DD + v] - Y / D) * (1.0f / (float)(SEQ - 1));
    float msum = attn, ssum = attn * attn;
#pragma unroll
    for (int m = 1; m < 64; m <<= 1) {
        msum += __shfl_xor(msum, m);
        ssum += __shfl_xor(ssum, m);
    }
    float mu = msum * (1.0f / 64.0f);
    float var = ssum * (1.0f / 64.0f) - mu * mu;
    float rs = rsqrtf(var + 1e-5f);
    out[(size_t)row * DD + v] = (attn - mu) * rs * gamma[v] + beta[v];
}

// ---------------------------------------------------------------------------
extern "C" void kernel_launch(void* const* d_in, const int* in_sizes, int n_in,
                              void* d_out, int out_size, void* d_ws, size_t ws_size,
                              hipStream_t stream) {
    const float* x1    = (const float*)d_in[0];
    const float* x2    = (const float*)d_in[1];
    const float* Wq    = (const float*)d_in[2];
    const float* bq    = (const float*)d_in[3];
    const float* Wk    = (const float*)d_in[4];
    const float* bk    = (const float*)d_in[5];
    const float* Wv    = (const float*)d_in[6];
    const float* bv    = (const float*)d_in[7];
    const float* gamma = (const float*)d_in[8];
    const float* beta  = (const float*)d_in[9];
    float* out = (float*)d_out;

    char* ws = (char*)d_ws;
    short* Qs  = (short*)(ws);                         // 2 MB  bf16 [16384][64]
    short* Kbf = (short*)(ws + (2ull << 20));          // 2 MB  bf16 [16384][64]
    short* Vtb = (short*)(ws + (4ull << 20));          // 2 MB  bf16 [8][64][2048]
    short* Wt  = (short*)(ws + (6ull << 20));          // 288 KB bf16 [3][64][768]
    float* Cc  = (float*)(ws + (6ull << 20) + 3 * DM * DD * 2);  // 2 KB f32 [8][64]
    short* Yp  = (short*)(ws + (7ull << 20));          // 4 MB  bf16 [2][16384][64]
    float* Dp  = (float*)(ws + (11ull << 20));         // 128 KB f32 [2][16384]

    prep_w_kernel<<<576, 256, 0, stream>>>(Wq, Wk, Wv, Wt, Cc);
    proj_kernel<<<1024, 128, 0, stream>>>(x1, x2, Wt, bq, bk, bv, Qs, Kbf, Vtb, Cc);
    flash_kernel<<<512, 256, 0, stream>>>(Qs, Kbf, Vtb, Yp, Dp);
    reduce_ln_kernel<<<BS / 4, 256, 0, stream>>>(Yp, Dp, Cc, gamma, beta, out);
}

// Round 9
// 171.091 us; speedup vs baseline: 1.0184x; 1.0184x over previous
//
#include <hip/hip_runtime.h>
#include <hip/hip_bf16.h>

// Shapes (fixed by the problem)
#define BATCH 8
#define SEQ   2048
#define DM    768
#define DD    64   // DK == DV == 64
#define BS (BATCH * SEQ)         // 16384
#define SCALEQ 0.1803369380478f  // (1/8) * log2(e): score in log2 domain

typedef __bf16 bf16x8 __attribute__((ext_vector_type(8)));
typedef float  f32x4  __attribute__((ext_vector_type(4)));
typedef short  short8 __attribute__((ext_vector_type(8)));
typedef short  short4v __attribute__((ext_vector_type(4)));

#define MFMA16(a, b, c) __builtin_amdgcn_mfma_f32_16x16x32_bf16((a), (b), (c), 0, 0, 0)

__device__ __forceinline__ short f2bf(float x) {
    unsigned u = __builtin_bit_cast(unsigned, x);
    u = (u + 0x7fffu + ((u >> 16) & 1u)) >> 16;   // round-to-nearest-even
    return (short)u;
}
__device__ __forceinline__ float bf2f(short s) {
    unsigned u = ((unsigned)(unsigned short)s) << 16;
    return __builtin_bit_cast(float, u);
}
__device__ __forceinline__ bf16x8 cvt8(float4 a, float4 b) {
    bf16x8 r;
    r[0] = (__bf16)a.x; r[1] = (__bf16)a.y; r[2] = (__bf16)a.z; r[3] = (__bf16)a.w;
    r[4] = (__bf16)b.x; r[5] = (__bf16)b.y; r[6] = (__bf16)b.z; r[7] = (__bf16)b.w;
    return r;
}

// ---------------------------------------------------------------------------
// Kernel 1: W [768][64] f32 -> Wt [3][64][768] bf16 (transposed, n-major).
// Wq pre-scaled by (1/8)*log2e so flash can use exp2. Zero-inits Cc.
// ---------------------------------------------------------------------------
__global__ void prep_w_kernel(const float* __restrict__ Wq, const float* __restrict__ Wk,
                              const float* __restrict__ Wv, short* __restrict__ Wt,
                              float* __restrict__ C) {
    int idx = blockIdx.x * 256 + threadIdx.x;
    if (idx < BATCH * DD) C[idx] = 0.f;
    if (idx >= 3 * DM * DD) return;
    int m = idx / (DM * DD);
    int r = (idx % (DM * DD)) / DD;
    int c = idx % DD;
    const float* W = (m == 0) ? Wq : (m == 1) ? Wk : Wv;
    float scale = (m == 0) ? SCALEQ : 1.0f;
    Wt[m * DM * DD + c * DM + r] = f2bf(W[r * DD + c] * scale);
}

// ---------------------------------------------------------------------------
// Kernel 2: projections — BARRIER-FREE k-loop (the per-iter barrier+vmcnt(0)
// drain with cold HBM loads was the 8200-cyc/iter stall; r7/r8 falsified the
// "more blocks/CU" fix). W staged in 4 large phases (192-k slabs, plain
// loads + ds_write, 2 barriers per phase = 8 total); between barriers the
// 6-step k-loop streams x A-frags as direct per-lane loads with rolling
// prefetch — the vmcnt queue is never drained, so loads pipeline to full
// Little's-law depth.
// even blocks = Q from x1 (stages Wq only); odd = K+V from x2 (Wk+Wv).
// 64 rows/block, 256 threads, LDS 50 KB, 512 blocks = 2/CU.
// LDS row stride 25 pieces (16B) -> b128 frag reads conflict-free.
// V stored transposed [b][v][s] + fused column-sum C via f32 atomics.
// ---------------------------------------------------------------------------
#define PHK 192   // k-width per phase
#define RSTR 200  // LDS row stride in shorts (25 pieces x 8)
__global__ __launch_bounds__(256) void proj_kernel(
        const float* __restrict__ x1, const float* __restrict__ x2,
        const short* __restrict__ Wt,
        const float* __restrict__ bq, const float* __restrict__ bk,
        const float* __restrict__ bv,
        short* __restrict__ Qs, short* __restrict__ Kb, short* __restrict__ Vtb,
        float* __restrict__ C) {
    __shared__ __align__(16) short wls[2][64 * RSTR];  // [mat][row][25 pieces]
    const int tid = threadIdx.x, wave = tid >> 6, lane = tid & 63;
    const int quad = lane >> 4, l15 = lane & 15;
    const int kv = blockIdx.x & 1;             // 0 = Q, 1 = K+V
    const int r0 = (blockIdx.x >> 1) * 64;
    const float* x = kv ? x2 : x1;
    const short* W0 = Wt + (kv ? (size_t)(DM * DD) : 0);
    const short* W1 = Wt + 2 * (size_t)(DM * DD);

    // staging geometry: thread -> row (tid>>2), k-segment (tid&3);
    // piece kp = kseg + 4*i, i=0..5  (64B-contiguous per 4 threads)
    const int srow = tid >> 2;
    const int skseg = tid & 3;

    const float* xp = x + (size_t)(r0 + wave * 16 + l15) * DM + quad * 8;

    f32x4 acc0[4] = {}, acc1[4] = {};

    // rolling x prefetch (one 32-k step ahead), issued before first barrier
    float4 cxa = *(const float4*)(xp);
    float4 cxb = *(const float4*)(xp + 4);

    for (int ph = 0; ph < 4; ph++) {
        const int kbase = ph * PHK;
        // stage W phase (plain loads + ds_write; L2-resident source)
#pragma unroll
        for (int i = 0; i < 6; i++) {
            int kp = skseg + 4 * i;
            bf16x8 w = *(const bf16x8*)(W0 + (size_t)srow * DM + kbase + kp * 8);
            *(bf16x8*)&wls[0][srow * RSTR + kp * 8] = w;
        }
        if (kv) {
#pragma unroll
            for (int i = 0; i < 6; i++) {
                int kp = skseg + 4 * i;
                bf16x8 w = *(const bf16x8*)(W1 + (size_t)srow * DM + kbase + kp * 8);
                *(bf16x8*)&wls[1][srow * RSTR + kp * 8] = w;
            }
        }
        __syncthreads();
        // 6 barrier-free k-steps
#pragma unroll
        for (int st = 0; st < 6; st++) {
            const int k0 = kbase + st * 32;
            float4 nxa, nxb;
            if (k0 + 32 < DM) {
                nxa = *(const float4*)(xp + k0 + 32);
                nxb = *(const float4*)(xp + k0 + 36);
            }
            bf16x8 af = cvt8(cxa, cxb);
#pragma unroll
            for (int tn = 0; tn < 4; tn++) {
                const int lofs = (tn * 16 + l15) * RSTR + (st * 4 + quad) * 8;
                acc0[tn] = MFMA16(af, *(const bf16x8*)&wls[0][lofs], acc0[tn]);
                if (kv)
                    acc1[tn] = MFMA16(af, *(const bf16x8*)&wls[1][lofs], acc1[tn]);
            }
            cxa = nxa; cxb = nxb;
        }
        __syncthreads();   // protect LDS before next phase's overwrite
    }

    if (!kv) {
#pragma unroll
        for (int tn = 0; tn < 4; tn++) {
            int v = tn * 16 + l15;
            float bb = bq[v] * SCALEQ;
#pragma unroll
            for (int r = 0; r < 4; r++)
                Qs[(size_t)(r0 + wave * 16 + quad * 4 + r) * DD + v] = f2bf(acc0[tn][r] + bb);
        }
    } else {
#pragma unroll
        for (int tn = 0; tn < 4; tn++) {
            int v = tn * 16 + l15;
            float bb = bk[v];
#pragma unroll
            for (int r = 0; r < 4; r++)
                Kb[(size_t)(r0 + wave * 16 + quad * 4 + r) * DD + v] = f2bf(acc0[tn][r] + bb);
        }
        const int b = r0 / SEQ;
        const int sbase = (r0 % SEQ) + wave * 16 + quad * 4;
#pragma unroll
        for (int tn = 0; tn < 4; tn++) {
            int v = tn * 16 + l15;
            float bb = bv[v];
            short4v pk;
            float cs = 0.f;
#pragma unroll
            for (int r = 0; r < 4; r++) {
                pk[r] = f2bf(acc1[tn][r] + bb);
                cs += bf2f(pk[r]);           // sum the rounded values (consistency)
            }
            *(short4v*)(Vtb + ((size_t)b * DD + v) * SEQ + sbase) = pk;
            cs += __shfl_xor(cs, 16);
            cs += __shfl_xor(cs, 32);
            if (quad == 0) atomicAdd(&C[b * DD + v], cs);
        }
    }
}

// ---------------------------------------------------------------------------
// Kernel 3: flash partial (round-5/7 verified structure): q-tile 64, waves
// own disjoint 256-s quarters of a 1024-s half; b = blk&7 for XCD L2
// affinity. Z^T = K.Q^T (log2 domain); per-wave LDS P^T transpose; no
// main-loop barriers. Emits 2 global halves: Yp bf16 + Dp f32.
// ---------------------------------------------------------------------------
#define PBS 72   // pbuf row stride (shorts)
__global__ __launch_bounds__(256, 2) void flash_kernel(
        const short* __restrict__ Q, const short* __restrict__ K,
        const short* __restrict__ Vt,
        short* __restrict__ Yp, float* __restrict__ Dp) {
    __shared__ __align__(16) short pbuf[4][64 * PBS];  // per-wave P^T / y-partials
    __shared__ float dl[4][64];
    const int tid  = threadIdx.x;
    const int wave = tid >> 6, lane = tid & 63, quad = lane >> 4, l15 = lane & 15;
    const int blk = blockIdx.x;
    const int b = blk & 7, qt = (blk >> 3) & 31, half = blk >> 8;
    const int q0 = qt * 64;

    bf16x8 qf[4][2];
#pragma unroll
    for (int qn = 0; qn < 4; qn++)
#pragma unroll
        for (int kc = 0; kc < 2; kc++)
            qf[qn][kc] = *(const bf16x8*)(Q + ((size_t)(b * SEQ + q0 + qn * 16 + l15)) * DD
                                          + kc * 32 + quad * 8);

    const short* Kbp = K  + (size_t)b * SEQ * DD;
    const short* Vbp = Vt + (size_t)b * DD * SEQ;
    f32x4 y[4][4] = {};          // [qn][vn]
    float den[4] = {0.f, 0.f, 0.f, 0.f};
    short* pw = &pbuf[wave][0];

    const int s_begin = half * 1024 + wave * 256;
    for (int s0 = s_begin; s0 < s_begin + 256; s0 += 64) {
        // Z^T = K.Q^T  (A = K rows s, B = Q)
#pragma unroll
        for (int tn = 0; tn < 4; tn++) {
            const short* kf = Kbp + (size_t)(s0 + tn * 16 + l15) * DD + quad * 8;
            bf16x8 ka0 = *(const bf16x8*)kf;
            bf16x8 ka1 = *(const bf16x8*)(kf + 32);
#pragma unroll
            for (int qn = 0; qn < 4; qn++) {
                f32x4 z = {0.f, 0.f, 0.f, 0.f};
                z = MFMA16(ka0, qf[qn][0], z);
                z = MFMA16(ka1, qf[qn][1], z);
                short4v pk;
#pragma unroll
                for (int r = 0; r < 4; r++) {
                    float p = __builtin_amdgcn_exp2f(z[r]);
                    den[qn] += p;
                    pk[r] = f2bf(p);
                }
                *(short4v*)&pw[(qn * 16 + l15) * PBS + tn * 16 + quad * 4] = pk;
            }
        }
        // Y^T += V^T.P^T
#pragma unroll
        for (int kc = 0; kc < 2; kc++) {
            bf16x8 pB[4];
#pragma unroll
            for (int qn = 0; qn < 4; qn++)
                pB[qn] = *(const bf16x8*)&pw[(qn * 16 + l15) * PBS + kc * 32 + quad * 8];
#pragma unroll
            for (int vn = 0; vn < 4; vn++) {
                bf16x8 va = *(const bf16x8*)(Vbp + (size_t)(vn * 16 + l15) * SEQ
                                             + s0 + kc * 32 + quad * 8);
#pragma unroll
                for (int qn = 0; qn < 4; qn++)
                    y[qn][vn] = MFMA16(va, pB[qn], y[qn][vn]);
            }
        }
    }
#pragma unroll
    for (int qn = 0; qn < 4; qn++) {
        den[qn] += __shfl_xor(den[qn], 16);
        den[qn] += __shfl_xor(den[qn], 32);
    }
#pragma unroll
    for (int qn = 0; qn < 4; qn++) {
#pragma unroll
        for (int vn = 0; vn < 4; vn++) {
            short4v pk;
#pragma unroll
            for (int r = 0; r < 4; r++) pk[r] = f2bf(y[qn][vn][r]);
            *(short4v*)&pw[(qn * 16 + l15) * PBS + vn * 16 + quad * 4] = pk;
        }
        if (quad == 0) dl[wave][qn * 16 + l15] = den[qn];
    }
    __syncthreads();
    // cross-wave reduce: wave handles q = wave*16+l15; quad covers 16 v's
    {
        const int q = wave * 16 + l15;
        float D = dl[0][q] + dl[1][q] + dl[2][q] + dl[3][q];
        float ys[16];
#pragma unroll
        for (int j = 0; j < 16; j++) ys[j] = 0.f;
#pragma unroll
        for (int u = 0; u < 4; u++) {
#pragma unroll
            for (int h = 0; h < 2; h++) {
                bf16x8 t = *(const bf16x8*)&pbuf[u][q * PBS + quad * 16 + h * 8];
#pragma unroll
                for (int j = 0; j < 8; j++) ys[h * 8 + j] += (float)t[j];
            }
        }
        const size_t row = (size_t)b * SEQ + q0 + q;
        short8 o0, o1;
#pragma unroll
        for (int j = 0; j < 8; j++) { o0[j] = f2bf(ys[j]); o1[j] = f2bf(ys[8 + j]); }
        short* yout = Yp + ((size_t)half * BS + row) * DD + quad * 16;
        *(short8*)yout = o0;
        *(short8*)(yout + 8) = o1;
        if (quad == 0) Dp[half * BS + row] = D;
    }
}

// ---------------------------------------------------------------------------
// Kernel 4: combine 2 halves + reverse transform + LayerNorm. One wave/q-row.
// ---------------------------------------------------------------------------
__global__ __launch_bounds__(256) void reduce_ln_kernel(
        const short* __restrict__ Yp, const float* __restrict__ Dp,
        const float* __restrict__ C, const float* __restrict__ gamma,
        const float* __restrict__ beta, float* __restrict__ out) {
    const int row = blockIdx.x * 4 + (threadIdx.x >> 6);
    const int v = threadIdx.x & 63;
    const int b = row >> 11;
    float Y = bf2f(Yp[(size_t)row * DD + v]) + bf2f(Yp[((size_t)BS + row) * DD + v]);
    float D = Dp[row] + Dp[BS + row];
    float attn = (C[b * DD + v] - Y / D) * (1.0f / (float)(SEQ - 1));
    float msum = attn, ssum = attn * attn;
#pragma unroll
    for (int m = 1; m < 64; m <<= 1) {
        msum += __shfl_xor(msum, m);
        ssum += __shfl_xor(ssum, m);
    }
    float mu = msum * (1.0f / 64.0f);
    float var = ssum * (1.0f / 64.0f) - mu * mu;
    float rs = rsqrtf(var + 1e-5f);
    out[(size_t)row * DD + v] = (attn - mu) * rs * gamma[v] + beta[v];
}

// ---------------------------------------------------------------------------
extern "C" void kernel_launch(void* const* d_in, const int* in_sizes, int n_in,
                              void* d_out, int out_size, void* d_ws, size_t ws_size,
                              hipStream_t stream) {
    const float* x1    = (const float*)d_in[0];
    const float* x2    = (const float*)d_in[1];
    const float* Wq    = (const float*)d_in[2];
    const float* bq    = (const float*)d_in[3];
    const float* Wk    = (const float*)d_in[4];
    const float* bk    = (const float*)d_in[5];
    const float* Wv    = (const float*)d_in[6];
    const float* bv    = (const float*)d_in[7];
    const float* gamma = (const float*)d_in[8];
    const float* beta  = (const float*)d_in[9];
    float* out = (float*)d_out;

    char* ws = (char*)d_ws;
    short* Qs  = (short*)(ws);                         // 2 MB  bf16 [16384][64]
    short* Kbf = (short*)(ws + (2ull << 20));          // 2 MB  bf16 [16384][64]
    short* Vtb = (short*)(ws + (4ull << 20));          // 2 MB  bf16 [8][64][2048]
    short* Wt  = (short*)(ws + (6ull << 20));          // 288 KB bf16 [3][64][768]
    float* Cc  = (float*)(ws + (6ull << 20) + 3 * DM * DD * 2);  // 2 KB f32 [8][64]
    short* Yp  = (short*)(ws + (7ull << 20));          // 4 MB  bf16 [2][16384][64]
    float* Dp  = (float*)(ws + (11ull << 20));         // 128 KB f32 [2][16384]

    prep_w_kernel<<<576, 256, 0, stream>>>(Wq, Wk, Wv, Wt, Cc);
    proj_kernel<<<512, 256, 0, stream>>>(x1, x2, Wt, bq, bk, bv, Qs, Kbf, Vtb, Cc);
    flash_kernel<<<512, 256, 0, stream>>>(Qs, Kbf, Vtb, Yp, Dp);
    reduce_ln_kernel<<<BS / 4, 256, 0, stream>>>(Yp, Dp, Cc, gamma, beta, out);
}